// Round 2
// baseline (129.810 us; speedup 1.0000x reference)
//
#include <hip/hip_runtime.h>

namespace {
constexpr int N_ = 16, C_ = 112, H_ = 48, W_ = 48, HW_ = 2304;
// ws float offsets
constexpr int WS_T7 = 0;         // N*H = 768
constexpr int WS_T17 = 768;      // N*7 = 112
constexpr int WS_A = 1024;       // N*C = 1792
constexpr int WS_V = 4096;       // N*C*7 = 12544
constexpr int WS_G = 16896;      // N*C*C = 200704
constexpr int WS_SPART = 217600; // nch*N*C*C
}

// ---------------------------------------------------------------------------
// K1: mx = mean_c(x) for a 12-row h-slab; t7[n,h] = sum_{k,w'} mx[...]*p7.
// NOTE ref: t3=roll(t1,+1,h) then t6=roll(t4,+1,h) => t7[h] uses mx rows (h-2)%48,
// i.e. value computed from mx row h' lands at t7[(h'+2)%48].
// grid (4, N), 192 threads
__global__ __launch_bounds__(192) void ath_stats(const float* __restrict__ x,
                                                 const float* __restrict__ p7,
                                                 float* __restrict__ ws) {
  const int hg = blockIdx.x;
  const int n = blockIdx.y;
  const int tid = threadIdx.x;
  __shared__ float mxs[576];
  float a0 = 0.f, a1 = 0.f, a2 = 0.f;
  const float* xb = x + (size_t)n * C_ * HW_ + hg * 576;
  for (int c = 0; c < C_; ++c) {
    const float* xc = xb + (size_t)c * HW_;
    a0 += xc[tid];
    a1 += xc[tid + 192];
    a2 += xc[tid + 384];
  }
  const float inv_c = 1.0f / (float)C_;
  mxs[tid] = a0 * inv_c;
  mxs[tid + 192] = a1 * inv_c;
  mxs[tid + 384] = a2 * inv_c;
  __syncthreads();
  if (tid < 12) {
    float s = 0.f;
    for (int k = 0; k < 3; ++k)
      for (int wp = 0; wp < W_; ++wp) {
        int j = 3 * k + wp - 3;
        if (j >= 0 && j < W_) s += mxs[tid * 48 + j] * p7[k * W_ + wp];
      }
    const int hsrc = hg * 12 + tid;
    const int hdst = (hsrc + 2) % 48;  // S3=+1, S6=+1 rolls compound to +2
    ws[WS_T7 + n * H_ + hdst] = s;
  }
}

// ---------------------------------------------------------------------------
// K2: t17[n,kk] = (1/48) sum_h |t7pad[n, 2kk+h-6]| ; grid N, 64 threads
__global__ __launch_bounds__(64) void ath_t17(float* __restrict__ ws) {
  const int n = blockIdx.x;
  const int tid = threadIdx.x;
  __shared__ float t7s[48];
  if (tid < 48) t7s[tid] = ws[WS_T7 + n * H_ + tid];
  __syncthreads();
  if (tid < 7) {
    float s = 0.f;
    for (int hh = 0; hh < 48; ++hh) {
      int j = 2 * tid + hh - 6;
      if (j >= 0 && j < 48) s += fabsf(t7s[j]);
    }
    ws[WS_T17 + n * 7 + tid] = s * (1.0f / 48.0f);
  }
}

// ---------------------------------------------------------------------------
// K3: per (n,c): V[n,c,m] = sum_{p: (w-h)%7==m} x ; A'[n,c]
// grid (C, N), 64 threads (one wave)
__global__ __launch_bounds__(64) void ath_colstats(const float* __restrict__ x,
                                                   const float* __restrict__ p19,
                                                   float* __restrict__ ws) {
  const int c = blockIdx.x, n = blockIdx.y;
  const int tid = threadIdx.x;
  const float* xb = x + ((size_t)n * C_ + c) * HW_;
  float rowsum = 0.f;
  if (tid < 48) {
    const float* xr = xb + tid * W_;
    for (int w = 0; w < W_; ++w) rowsum += xr[w];
  }
  float vb[7] = {0.f, 0.f, 0.f, 0.f, 0.f, 0.f, 0.f};
  for (int jj = 0; jj < HW_ / 64; ++jj) {
    int p = tid + 64 * jj;
    float v = xb[p];
    int h = p / 48;
    int w = p - h * 48;
    int m = (w - h + 49) % 7;
#pragma unroll
    for (int j = 0; j < 7; ++j) vb[j] += (m == j) ? v : 0.f;
  }
#pragma unroll
  for (int j = 0; j < 7; ++j) {
#pragma unroll
    for (int off = 32; off >= 1; off >>= 1) vb[j] += __shfl_xor(vb[j], off);
  }
  if (tid == 0) {
#pragma unroll
    for (int j = 0; j < 7; ++j) ws[WS_V + ((size_t)n * C_ + c) * 7 + j] = vb[j];
  }
  // A'[n,c] = (2/48) * p19[c] * sum_h t7[h]*(rowsum[h] + D[(c-h)%7]),
  // D[s] = 7*T - t17[(s+6)%7], T = sum t17
  const float* t7p = ws + WS_T7 + n * H_;
  const float* t17p = ws + WS_T17 + n * 7;
  float T = 0.f;
#pragma unroll
  for (int j = 0; j < 7; ++j) T += t17p[j];
  float term = 0.f;
  if (tid < 48) {
    int idx6 = ((c - tid + 6) % 7 + 7) % 7;
    float D = 7.f * T - t17p[idx6];
    term = t7p[tid] * (rowsum + D);
  }
#pragma unroll
  for (int off = 32; off >= 1; off >>= 1) term += __shfl_xor(term, off);
  if (tid == 0) ws[WS_A + n * C_ + c] = p19[c] * term * (2.0f / 48.0f);
}

// ---------------------------------------------------------------------------
// K4: Gram partials S_part[n,kc][c][i] = sum_{p in chunk} x[c,p]*x[i,p]
// grid N*nch, 256 threads, 7x7 per-thread tile, K staged in LDS (96 at a time)
__global__ __launch_bounds__(256) void ath_gram(const float* __restrict__ x,
                                                float* __restrict__ ws,
                                                int nch, int KC) {
  const int bid = blockIdx.x;
  const int n = bid / nch;
  const int kc = bid - n * nch;
  const int p0 = kc * KC;
  const int tid = threadIdx.x;
  __shared__ float xs[96][C_ + 1];
  float acc[7][7];
#pragma unroll
  for (int a = 0; a < 7; ++a)
#pragma unroll
    for (int b = 0; b < 7; ++b) acc[a][b] = 0.f;
  const int tc = tid >> 4, ti = tid & 15;
  const int c0 = tc * 7, i0 = ti * 7;
  const float* xb = x + (size_t)n * C_ * HW_;
  for (int ks = 0; ks < KC; ks += 96) {
    __syncthreads();
    for (int idx = tid; idx < C_ * 96; idx += 256) {
      int cc = idx / 96, k = idx - cc * 96;
      xs[k][cc] = xb[(size_t)cc * HW_ + p0 + ks + k];
    }
    __syncthreads();
#pragma unroll 2
    for (int k = 0; k < 96; ++k) {
      float a[7], b[7];
#pragma unroll
      for (int j = 0; j < 7; ++j) a[j] = xs[k][c0 + j];
#pragma unroll
      for (int j = 0; j < 7; ++j) b[j] = xs[k][i0 + j];
#pragma unroll
      for (int aj = 0; aj < 7; ++aj)
#pragma unroll
        for (int bj = 0; bj < 7; ++bj) acc[aj][bj] += a[aj] * b[bj];
    }
  }
  float* sp = ws + WS_SPART + (size_t)bid * (C_ * C_);
#pragma unroll
  for (int aj = 0; aj < 7; ++aj)
#pragma unroll
    for (int bj = 0; bj < 7; ++bj) sp[(c0 + aj) * C_ + i0 + bj] = acc[aj][bj];
}

// ---------------------------------------------------------------------------
// K5: G'[n,c,i] = p19[c]*(S + sum_m t17[(c+m)%7]*V[n,i,m]) / (48*sqrt(112))
__global__ __launch_bounds__(256) void ath_assemble(const float* __restrict__ p19,
                                                    float* __restrict__ ws,
                                                    int nch) {
  const int idx = blockIdx.x * 256 + threadIdx.x;
  if (idx >= N_ * C_ * C_) return;
  const int n = idx / (C_ * C_);
  const int r = idx - n * (C_ * C_);
  const int c = r / C_;
  const int i = r - c * C_;
  float s = 0.f;
  for (int kc = 0; kc < nch; ++kc)
    s += ws[WS_SPART + (size_t)(n * nch + kc) * (C_ * C_) + r];
  const float* t17p = ws + WS_T17 + n * 7;
  const float* vp = ws + WS_V + ((size_t)n * C_ + i) * 7;
  float t = 0.f;
#pragma unroll
  for (int m = 0; m < 7; ++m) t += t17p[(c + m) % 7] * vp[m];
  const float scale = 1.0f / (48.0f * sqrtf(112.0f));
  ws[WS_G + idx] = p19[c] * (s + t) * scale;
}

// ---------------------------------------------------------------------------
// K6 fused: per (n,h): compute t13 row tile (conv(-x) maxed with x) into LDS,
// then out[c, h, w] = A'[n,c] - sum_i G'[n,c,i] * t13[i, h*48+w]
// grid (H, N), 256 threads (192 active compute lanes: 16 o-groups x 12 w-groups)
__global__ __launch_bounds__(256) void ath_fused(const float* __restrict__ x,
                                                 const float* __restrict__ cw,
                                                 const float* __restrict__ ws,
                                                 float* __restrict__ out) {
  const int h = blockIdx.x, n = blockIdx.y;
  const int tid = threadIdx.x;
  __shared__ float xs[C_][W_ + 4];  // x row slab, padded +/-2 with zeros
  __shared__ float t13s[C_][W_];
  const float* xb = x + (size_t)n * C_ * HW_ + h * W_;  // [i*HW_ + w]
  for (int idx = tid; idx < C_ * (W_ + 4); idx += 256) {
    int i = idx / (W_ + 4), ww = idx - i * (W_ + 4);
    int w = ww - 2;
    xs[i][ww] = (w >= 0 && w < W_) ? xb[(size_t)i * HW_ + w] : 0.f;
  }
  __syncthreads();
  const int og = tid / 12, wq = tid - og * 12;
  const int o0 = og * 7, w0 = wq * 4;
  if (tid < 192) {
    // conv: t11[o, w] = -sum_{i,kx} x[i, w+2kx-2]*cw[o,i,kx]; t13 = max(t11, x)
    float acc[7][4];
#pragma unroll
    for (int j = 0; j < 7; ++j)
#pragma unroll
      for (int l = 0; l < 4; ++l) acc[j][l] = 0.f;
    for (int ii = 0; ii < C_; ii += 4) {
      float u[4][8];
#pragma unroll
      for (int r = 0; r < 4; ++r) {
        float4 ua = *(const float4*)&xs[ii + r][w0];
        float4 ub = *(const float4*)&xs[ii + r][w0 + 4];
        u[r][0] = ua.x; u[r][1] = ua.y; u[r][2] = ua.z; u[r][3] = ua.w;
        u[r][4] = ub.x; u[r][5] = ub.y; u[r][6] = ub.z; u[r][7] = ub.w;
      }
#pragma unroll
      for (int j = 0; j < 7; ++j) {
        const float4* cwp = (const float4*)&cw[((size_t)(o0 + j) * C_ + ii) * 3];
        float4 ca = cwp[0], cb = cwp[1], cc = cwp[2];
        float cv[12];
        cv[0] = ca.x; cv[1] = ca.y; cv[2] = ca.z; cv[3] = ca.w;
        cv[4] = cb.x; cv[5] = cb.y; cv[6] = cb.z; cv[7] = cb.w;
        cv[8] = cc.x; cv[9] = cc.y; cv[10] = cc.z; cv[11] = cc.w;
#pragma unroll
        for (int di = 0; di < 4; ++di)
#pragma unroll
          for (int kx = 0; kx < 3; ++kx) {
            float wv = cv[di * 3 + kx];
#pragma unroll
            for (int l = 0; l < 4; ++l) acc[j][l] += wv * u[di][l + 2 * kx];
          }
      }
    }
#pragma unroll
    for (int j = 0; j < 7; ++j)
#pragma unroll
      for (int l = 0; l < 4; ++l) {
        float xv = xs[o0 + j][w0 + l + 2];
        t13s[o0 + j][w0 + l] = fmaxf(-acc[j][l], xv);
      }
  }
  __syncthreads();
  if (tid < 192) {
    const float* gp = ws + WS_G + (size_t)n * C_ * C_;
    float acc[7][4];
#pragma unroll
    for (int j = 0; j < 7; ++j)
#pragma unroll
      for (int l = 0; l < 4; ++l) acc[j][l] = 0.f;
    for (int i = 0; i < C_; i += 4) {
      float s4[4][4];
#pragma unroll
      for (int r = 0; r < 4; ++r) {
        float4 t = *(const float4*)&t13s[i + r][w0];
        s4[r][0] = t.x; s4[r][1] = t.y; s4[r][2] = t.z; s4[r][3] = t.w;
      }
#pragma unroll
      for (int j = 0; j < 7; ++j) {
        float4 g = *(const float4*)&gp[(size_t)(o0 + j) * C_ + i];
        float ga[4] = {g.x, g.y, g.z, g.w};
#pragma unroll
        for (int r = 0; r < 4; ++r)
#pragma unroll
          for (int l = 0; l < 4; ++l) acc[j][l] += ga[r] * s4[r][l];
      }
    }
#pragma unroll
    for (int j = 0; j < 7; ++j) {
      float ap = ws[WS_A + n * C_ + o0 + j];
      float4 o;
      o.x = ap - acc[j][0];
      o.y = ap - acc[j][1];
      o.z = ap - acc[j][2];
      o.w = ap - acc[j][3];
      *(float4*)&out[((size_t)n * C_ + o0 + j) * HW_ + h * W_ + w0] = o;
    }
  }
}

// ---------------------------------------------------------------------------
extern "C" void kernel_launch(void* const* d_in, const int* in_sizes, int n_in,
                              void* d_out, int out_size, void* d_ws, size_t ws_size,
                              hipStream_t stream) {
  const float* x = (const float*)d_in[0];
  const float* p7 = (const float*)d_in[1];
  // d_in[2] (p8_w) cancels algebraically: t10 = t8 - (x + t8) = -x
  const float* p19 = (const float*)d_in[3];
  const float* cw = (const float*)d_in[4];
  float* ws = (float*)d_ws;
  float* out = (float*)d_out;

  int nch = 12;
  for (;;) {
    size_t need = ((size_t)WS_SPART + (size_t)nch * N_ * C_ * C_) * sizeof(float);
    if (need <= ws_size || nch == 1) break;
    nch = (nch == 12) ? 6 : (nch == 6) ? 3 : 1;
  }
  const int KC = HW_ / nch;

  ath_stats<<<dim3(4, N_), 192, 0, stream>>>(x, p7, ws);
  ath_t17<<<N_, 64, 0, stream>>>(ws);
  ath_colstats<<<dim3(C_, N_), 64, 0, stream>>>(x, p19, ws);
  ath_gram<<<N_ * nch, 256, 0, stream>>>(x, ws, nch, KC);
  ath_assemble<<<(N_ * C_ * C_ + 255) / 256, 256, 0, stream>>>(p19, ws, nch);
  ath_fused<<<dim3(H_, N_), 256, 0, stream>>>(x, cw, ws, out);
}